// Round 1
// baseline (1120.766 us; speedup 1.0000x reference)
//
#include <hip/hip_runtime.h>
#include <hip/hip_bf16.h>

// ---------------------------------------------------------------------------
// GNN: hiddens = relu(gcn(x,W1,b1)); emb = gcn(hiddens,W2,b2);
// pred_i/j = <emb[r,y,:],emb[c,y,:]> at head y[r]/y[c].
//
// aggregate-then-transform: A_norm @ (H @ W) = (A_norm @ H) @ W.
// CSR build: count -> 3-phase parallel scan -> atomic fill with per-edge norm.
// GEMM: 128x128 tile, 8x8 per-thread register outer product, X staged
// transposed in LDS (stride 130 -> conflict-free hot-loop reads).
// ---------------------------------------------------------------------------

#define SCAN_SEG 512   // elements per scan block (256 threads x 2)

__global__ void count_kernel(const int* __restrict__ dst, int* __restrict__ cnt, int E) {
    int e = blockIdx.x * blockDim.x + threadIdx.x;
    if (e < E) atomicAdd(&cnt[dst[e]], 1);
}

// phase 1: per-block segment sums (coalesced)
__global__ __launch_bounds__(256) void blocksum_kernel(const int* __restrict__ cnt,
                                                       int* __restrict__ blocksum, int n) {
    __shared__ int red[4];
    int b = blockIdx.x, t = threadIdx.x;
    int i0 = b * SCAN_SEG + t;
    int s = 0;
    if (i0 < n) s += cnt[i0];
    if (i0 + 256 < n) s += cnt[i0 + 256];
#pragma unroll
    for (int off = 32; off >= 1; off >>= 1) s += __shfl_xor(s, off, 64);
    if ((t & 63) == 0) red[t >> 6] = s;
    __syncthreads();
    if (t == 0) blocksum[b] = red[0] + red[1] + red[2] + red[3];
}

// phase 2: exclusive scan of <=256 block sums in one small block
__global__ __launch_bounds__(256) void blockscan_kernel(const int* __restrict__ blocksum,
                                                        int* __restrict__ blockoff, int nb,
                                                        int* __restrict__ row_ptr, int n, int E) {
    __shared__ int s[256];
    int t = threadIdx.x;
    int v = (t < nb) ? blocksum[t] : 0;
    s[t] = v;
    __syncthreads();
    for (int off = 1; off < 256; off <<= 1) {
        int u = (t >= off) ? s[t - off] : 0;
        __syncthreads();
        s[t] += u;
        __syncthreads();
    }
    if (t < nb) blockoff[t] = s[t] - v;   // exclusive
    if (t == 0) row_ptr[n] = E;
}

// phase 3: per-block exclusive scan over its 512-elem segment -> row_ptr/cursor/dinv
__global__ __launch_bounds__(256) void csr_ptr_kernel(const int* __restrict__ cnt,
                                                      const int* __restrict__ blockoff,
                                                      int* __restrict__ row_ptr,
                                                      int* __restrict__ cursor,
                                                      float* __restrict__ dinv, int n) {
    __shared__ int s[256];
    int b = blockIdx.x, t = threadIdx.x;
    int i0 = b * SCAN_SEG + 2 * t;       // thread handles i0, i0+1
    int c0 = (i0     < n) ? cnt[i0]     : 0;
    int c1 = (i0 + 1 < n) ? cnt[i0 + 1] : 0;
    int pair = c0 + c1;
    s[t] = pair;
    __syncthreads();
    for (int off = 1; off < 256; off <<= 1) {
        int u = (t >= off) ? s[t - off] : 0;
        __syncthreads();
        s[t] += u;
        __syncthreads();
    }
    int excl = s[t] - pair + blockoff[b];
    if (i0 < n) {
        row_ptr[i0] = excl;
        cursor[i0]  = excl;
        dinv[i0]    = rsqrtf((float)(c0 + 1));
    }
    if (i0 + 1 < n) {
        row_ptr[i0 + 1] = excl + c0;
        cursor[i0 + 1]  = excl + c0;
        dinv[i0 + 1]    = rsqrtf((float)(c1 + 1));
    }
}

__global__ void fill_kernel(const int* __restrict__ src, const int* __restrict__ dst,
                            int* __restrict__ cursor, const float* __restrict__ dinv,
                            int* __restrict__ csr_src, float* __restrict__ csr_wt, int E) {
    int e = blockIdx.x * blockDim.x + threadIdx.x;
    if (e < E) {
        int s = src[e], d = dst[e];
        int pos = atomicAdd(&cursor[d], 1);
        csr_src[pos] = s;
        csr_wt[pos]  = dinv[s] * dinv[d];
    }
}

// out[node,f] = dinv[node]^2 * feat[node,f] + sum_e csr_wt[e]*feat[csr_src[e],f]
__global__ __launch_bounds__(128) void agg_kernel(const float* __restrict__ feat,
                                                  const int* __restrict__ row_ptr,
                                                  const int* __restrict__ csr_src,
                                                  const float* __restrict__ csr_wt,
                                                  const float* __restrict__ dinv,
                                                  float* __restrict__ out, int n) {
    int node = blockIdx.x;
    int f = threadIdx.x;
    float di = dinv[node];
    float acc = feat[(size_t)node * 128 + f] * di * di;   // self-loop
    int e0 = row_ptr[node], e1 = row_ptr[node + 1];
    int e = e0;
    for (; e + 4 <= e1; e += 4) {
        int s0 = csr_src[e],   s1 = csr_src[e+1], s2 = csr_src[e+2], s3 = csr_src[e+3];
        float w0 = csr_wt[e],  w1 = csr_wt[e+1],  w2 = csr_wt[e+2],  w3 = csr_wt[e+3];
        float v0 = feat[(size_t)s0 * 128 + f];
        float v1 = feat[(size_t)s1 * 128 + f];
        float v2 = feat[(size_t)s2 * 128 + f];
        float v3 = feat[(size_t)s3 * 128 + f];
        acc += v0 * w0 + v1 * w1 + v2 * w2 + v3 * w3;
    }
    for (; e < e1; ++e)
        acc += feat[(size_t)csr_src[e] * 128 + f] * csr_wt[e];
    out[(size_t)node * 128 + f] = acc;
}

// C[N, 128-col chunk] = X[N,128] @ W[128, ldw] + bias, optional relu.
// BM=BN=128, 256 threads, per-thread 8x8 outer product (2x2 float4 blocks).
// Xs holds the X tile TRANSPOSED [k][m] with row stride 130 floats:
//   hot-loop read bank = (2k + 4*tm) % 32 -> 4 distinct granules/wave, free.
//   transpose ds_write_b128 lands 2-way (free per m136), one-time cost.
__global__ __launch_bounds__(256, 1) void gemm_rm(const float* __restrict__ X,
                                                  const float* __restrict__ W,
                                                  const float* __restrict__ bias,
                                                  float* __restrict__ C,
                                                  int N, int ldw, int do_relu) {
    __shared__ float Xs[128 * 130];   // 66560 B, [k][m] transposed, stride 130
    __shared__ float Ws[128 * 128];   // 65536 B, [k][n]

    const int tid    = threadIdx.x;
    const int tn     = tid & 15;      // col group 0..15
    const int tm     = tid >> 4;      // row group 0..15
    const int row0   = blockIdx.y * 128;
    const int colOff = blockIdx.x * 128;

    // ---- stage W chunk [128][128], coalesced both sides ----
    for (int i = tid; i < 128 * 32; i += 256) {
        int kr = i >> 5, c4 = i & 31;
        *(float4*)(Ws + kr * 128 + c4 * 4) =
            *(const float4*)(W + (size_t)kr * ldw + colOff + c4 * 4);
    }

    // ---- stage X tile transposed via per-thread 4x4 blocks ----
    {
        const int mb  = tid >> 3;     // m-block 0..31
        const int kq8 = tid & 7;      // k-quad low 0..7
        const int r0  = row0 + 4 * mb;
        const int ra = (r0     < N) ? r0     : N - 1;
        const int rb = (r0 + 1 < N) ? r0 + 1 : N - 1;
        const int rc = (r0 + 2 < N) ? r0 + 2 : N - 1;
        const int rd = (r0 + 3 < N) ? r0 + 3 : N - 1;
#pragma unroll
        for (int p = 0; p < 4; ++p) {
            int kq = kq8 + 8 * p;     // 0..31
            float4 v0 = *(const float4*)(X + (size_t)ra * 128 + 4 * kq);
            float4 v1 = *(const float4*)(X + (size_t)rb * 128 + 4 * kq);
            float4 v2 = *(const float4*)(X + (size_t)rc * 128 + 4 * kq);
            float4 v3 = *(const float4*)(X + (size_t)rd * 128 + 4 * kq);
            float* dst = Xs + (size_t)(4 * kq) * 130 + 4 * mb;
            *(float4*)(dst        ) = make_float4(v0.x, v1.x, v2.x, v3.x);
            *(float4*)(dst + 130  ) = make_float4(v0.y, v1.y, v2.y, v3.y);
            *(float4*)(dst + 260  ) = make_float4(v0.z, v1.z, v2.z, v3.z);
            *(float4*)(dst + 390  ) = make_float4(v0.w, v1.w, v2.w, v3.w);
        }
    }
    __syncthreads();

    // ---- main loop: 8x8 register outer product ----
    float4 acc[8][2];
#pragma unroll
    for (int i = 0; i < 8; ++i) {
        acc[i][0] = make_float4(0.f, 0.f, 0.f, 0.f);
        acc[i][1] = make_float4(0.f, 0.f, 0.f, 0.f);
    }

#pragma unroll 4
    for (int k = 0; k < 128; ++k) {
        const float4 xa = *(const float4*)(Xs + k * 130 + 4 * tm);
        const float4 xb = *(const float4*)(Xs + k * 130 + 64 + 4 * tm);
        const float4 wa = *(const float4*)(Ws + k * 128 + 4 * tn);
        const float4 wb = *(const float4*)(Ws + k * 128 + 64 + 4 * tn);
        const float xr[8] = {xa.x, xa.y, xa.z, xa.w, xb.x, xb.y, xb.z, xb.w};
#pragma unroll
        for (int i = 0; i < 8; ++i) {
            acc[i][0].x += xr[i] * wa.x;
            acc[i][0].y += xr[i] * wa.y;
            acc[i][0].z += xr[i] * wa.z;
            acc[i][0].w += xr[i] * wa.w;
            acc[i][1].x += xr[i] * wb.x;
            acc[i][1].y += xr[i] * wb.y;
            acc[i][1].z += xr[i] * wb.z;
            acc[i][1].w += xr[i] * wb.w;
        }
    }

    // ---- epilogue: bias (+relu), coalesced float4 stores ----
    const float4 ba = *(const float4*)(bias + colOff + 4 * tn);
    const float4 bb = *(const float4*)(bias + colOff + 64 + 4 * tn);
#pragma unroll
    for (int i = 0; i < 8; ++i) {
        int r = row0 + ((i < 4) ? (4 * tm + i) : (64 + 4 * tm + (i - 4)));
        if (r < N) {
            float4 c0 = acc[i][0], c1 = acc[i][1];
            c0.x += ba.x; c0.y += ba.y; c0.z += ba.z; c0.w += ba.w;
            c1.x += bb.x; c1.y += bb.y; c1.z += bb.z; c1.w += bb.w;
            if (do_relu) {
                c0.x = fmaxf(c0.x, 0.f); c0.y = fmaxf(c0.y, 0.f);
                c0.z = fmaxf(c0.z, 0.f); c0.w = fmaxf(c0.w, 0.f);
                c1.x = fmaxf(c1.x, 0.f); c1.y = fmaxf(c1.y, 0.f);
                c1.z = fmaxf(c1.z, 0.f); c1.w = fmaxf(c1.w, 0.f);
            }
            *(float4*)(C + (size_t)r * ldw + colOff + 4 * tn)      = c0;
            *(float4*)(C + (size_t)r * ldw + colOff + 64 + 4 * tn) = c1;
        }
    }
}

// one 64-lane wave per query edge; load only the two selected heads (1 KB/edge)
__global__ __launch_bounds__(256) void query_kernel(const float* __restrict__ emb,
                                                    const int* __restrict__ qrow,
                                                    const int* __restrict__ qcol,
                                                    const int* __restrict__ y,
                                                    float* __restrict__ pred_i,
                                                    float* __restrict__ pred_j,
                                                    float* __restrict__ pred, int Q) {
    int wave = (int)((blockIdx.x * 256 + threadIdx.x) >> 6);
    int lane = threadIdx.x & 63;
    if (wave >= Q) return;
    int r = qrow[wave], c = qcol[wave];
    int yi = y[r], yj = y[c];   // same-address across wave -> broadcast
    const float* er = emb + (size_t)r * 512;
    const float* ec = emb + (size_t)c * 512;
    float pi = er[yi * 64 + lane] * ec[yi * 64 + lane];
    float pj = er[yj * 64 + lane] * ec[yj * 64 + lane];
#pragma unroll
    for (int off = 32; off >= 1; off >>= 1) {
        pi += __shfl_xor(pi, off, 64);
        pj += __shfl_xor(pj, off, 64);
    }
    if (lane == 0) {
        pred_i[wave] = pi;
        pred_j[wave] = pj;
        pred[wave]   = 0.5f * (pi + pj);
    }
}

extern "C" void kernel_launch(void* const* d_in, const int* in_sizes, int n_in,
                              void* d_out, int out_size, void* d_ws, size_t ws_size,
                              hipStream_t stream) {
    const float* x   = (const float*)d_in[0];
    const float* W1  = (const float*)d_in[1];
    const float* b1  = (const float*)d_in[2];
    const float* W2  = (const float*)d_in[3];
    const float* b2  = (const float*)d_in[4];
    const int* edge  = (const int*)d_in[5];
    const int* qedge = (const int*)d_in[6];
    const int* y     = (const int*)d_in[7];

    const int N = in_sizes[0] / 128;   // 100000
    const int E = in_sizes[5] / 2;     // 1600000
    const int Q = in_sizes[6] / 2;     // 400000

    float* out     = (float*)d_out;
    float* hiddens = out;                         // [N,128]
    float* emb     = out + (size_t)N * 128;       // [N,512]
    float* pred_i  = emb + (size_t)N * 512;       // [Q]
    float* pred_j  = pred_i + Q;                  // [Q]
    float* pred    = pred_j + Q;                  // [Q]

    // workspace carve (256B aligned)
    char* w = (char*)d_ws;
    auto alloc = [&](size_t bytes) { char* p = w; w += (bytes + 255) & ~(size_t)255; return p; };
    int*   cnt      = (int*)alloc((size_t)N * 4);
    int*   row_ptr  = (int*)alloc((size_t)(N + 1) * 4);
    int*   cursor   = (int*)alloc((size_t)N * 4);
    float* dinv     = (float*)alloc((size_t)N * 4);
    int*   csr_src  = (int*)alloc((size_t)E * 4);
    float* csr_wt   = (float*)alloc((size_t)E * 4);
    int*   blocksum = (int*)alloc(256 * 4);
    int*   blockoff = (int*)alloc(256 * 4);
    float* aggbuf   = (float*)alloc((size_t)N * 128 * 4);  // 51.2 MB, reused

    const int* esrc = edge;         const int* edst = edge + E;
    const int* qrow = qedge;        const int* qcol = qedge + Q;

    const int nb = (N + SCAN_SEG - 1) / SCAN_SEG;   // 196 <= 256

    hipMemsetAsync(cnt, 0, (size_t)N * 4, stream);
    count_kernel<<<dim3((E + 255) / 256), dim3(256), 0, stream>>>(edst, cnt, E);
    blocksum_kernel<<<dim3(nb), dim3(256), 0, stream>>>(cnt, blocksum, N);
    blockscan_kernel<<<dim3(1), dim3(256), 0, stream>>>(blocksum, blockoff, nb, row_ptr, N, E);
    csr_ptr_kernel<<<dim3(nb), dim3(256), 0, stream>>>(cnt, blockoff, row_ptr, cursor, dinv, N);
    fill_kernel<<<dim3((E + 255) / 256), dim3(256), 0, stream>>>(esrc, edst, cursor, dinv, csr_src, csr_wt, E);

    const int mblocks = (N + 127) / 128;   // 782

    // layer 1: aggregate x, then GEMM with fused bias+relu
    agg_kernel<<<dim3(N), dim3(128), 0, stream>>>(x, row_ptr, csr_src, csr_wt, dinv, aggbuf, N);
    gemm_rm<<<dim3(1, mblocks), dim3(256), 0, stream>>>(aggbuf, W1, b1, hiddens, N, 128, 1);

    // layer 2: aggregate hiddens, then GEMM with fused bias
    agg_kernel<<<dim3(N), dim3(128), 0, stream>>>(hiddens, row_ptr, csr_src, csr_wt, dinv, aggbuf, N);
    gemm_rm<<<dim3(4, mblocks), dim3(256), 0, stream>>>(aggbuf, W2, b2, emb, N, 512, 0);

    query_kernel<<<dim3((Q + 3) / 4), dim3(256), 0, stream>>>(emb, qrow, qcol, y, pred_i, pred_j, pred, Q);
}

// Round 2
// 962.453 us; speedup vs baseline: 1.1645x; 1.1645x over previous
//
#include <hip/hip_runtime.h>
#include <hip/hip_bf16.h>

// ---------------------------------------------------------------------------
// GNN: hiddens = relu(gcn(x,W1,b1)); emb = gcn(hiddens,W2,b2);
// pred_i/j = <emb[r,y,:],emb[c,y,:]> at head y[r]/y[c].
//
// aggregate-then-transform: A_norm @ (H @ W) = (A_norm @ H) @ W.
// CSR build: count -> 3-phase parallel scan -> atomic fill with per-edge norm.
// GEMM: split-bf16 MFMA (C = Ah*Bh + Ah*Bl + Al*Bh, fp32 accumulate).
//   128x128 tile, 4 waves (2x2), wave tile 64x64 = 4x4 frags of 16x16x32.
//   BK=64 two-phase staging -> 64KB LDS -> 2 blocks/CU (round-1 lesson:
//   1 block/CU = occupancy cliff). XOR swizzle ((row&7)<<4) on LDS k-bytes,
//   applied on BOTH write and read sides.
// ---------------------------------------------------------------------------

#define SCAN_SEG 512   // elements per scan block (256 threads x 2)

typedef short bf16x8 __attribute__((ext_vector_type(8)));   // 8 bf16 in 4 VGPRs
typedef float f32x4  __attribute__((ext_vector_type(4)));

__device__ __forceinline__ ushort f2bf(float x) {           // truncate: lo term catches residual
    return (ushort)(__float_as_uint(x) >> 16);
}
__device__ __forceinline__ float bf2f(ushort h) {
    return __uint_as_float(((unsigned)h) << 16);
}

__global__ void count_kernel(const int* __restrict__ dst, int* __restrict__ cnt, int E) {
    int e = blockIdx.x * blockDim.x + threadIdx.x;
    if (e < E) atomicAdd(&cnt[dst[e]], 1);
}

// phase 1: per-block segment sums (coalesced)
__global__ __launch_bounds__(256) void blocksum_kernel(const int* __restrict__ cnt,
                                                       int* __restrict__ blocksum, int n) {
    __shared__ int red[4];
    int b = blockIdx.x, t = threadIdx.x;
    int i0 = b * SCAN_SEG + t;
    int s = 0;
    if (i0 < n) s += cnt[i0];
    if (i0 + 256 < n) s += cnt[i0 + 256];
#pragma unroll
    for (int off = 32; off >= 1; off >>= 1) s += __shfl_xor(s, off, 64);
    if ((t & 63) == 0) red[t >> 6] = s;
    __syncthreads();
    if (t == 0) blocksum[b] = red[0] + red[1] + red[2] + red[3];
}

// phase 2: exclusive scan of <=256 block sums in one small block
__global__ __launch_bounds__(256) void blockscan_kernel(const int* __restrict__ blocksum,
                                                        int* __restrict__ blockoff, int nb,
                                                        int* __restrict__ row_ptr, int n, int E) {
    __shared__ int s[256];
    int t = threadIdx.x;
    int v = (t < nb) ? blocksum[t] : 0;
    s[t] = v;
    __syncthreads();
    for (int off = 1; off < 256; off <<= 1) {
        int u = (t >= off) ? s[t - off] : 0;
        __syncthreads();
        s[t] += u;
        __syncthreads();
    }
    if (t < nb) blockoff[t] = s[t] - v;   // exclusive
    if (t == 0) row_ptr[n] = E;
}

// phase 3: per-block exclusive scan over its 512-elem segment -> row_ptr/cursor/dinv
__global__ __launch_bounds__(256) void csr_ptr_kernel(const int* __restrict__ cnt,
                                                      const int* __restrict__ blockoff,
                                                      int* __restrict__ row_ptr,
                                                      int* __restrict__ cursor,
                                                      float* __restrict__ dinv, int n) {
    __shared__ int s[256];
    int b = blockIdx.x, t = threadIdx.x;
    int i0 = b * SCAN_SEG + 2 * t;       // thread handles i0, i0+1
    int c0 = (i0     < n) ? cnt[i0]     : 0;
    int c1 = (i0 + 1 < n) ? cnt[i0 + 1] : 0;
    int pair = c0 + c1;
    s[t] = pair;
    __syncthreads();
    for (int off = 1; off < 256; off <<= 1) {
        int u = (t >= off) ? s[t - off] : 0;
        __syncthreads();
        s[t] += u;
        __syncthreads();
    }
    int excl = s[t] - pair + blockoff[b];
    if (i0 < n) {
        row_ptr[i0] = excl;
        cursor[i0]  = excl;
        dinv[i0]    = rsqrtf((float)(c0 + 1));
    }
    if (i0 + 1 < n) {
        row_ptr[i0 + 1] = excl + c0;
        cursor[i0 + 1]  = excl + c0;
        dinv[i0 + 1]    = rsqrtf((float)(c1 + 1));
    }
}

__global__ void fill_kernel(const int* __restrict__ src, const int* __restrict__ dst,
                            int* __restrict__ cursor, const float* __restrict__ dinv,
                            int* __restrict__ csr_src, float* __restrict__ csr_wt, int E) {
    int e = blockIdx.x * blockDim.x + threadIdx.x;
    if (e < E) {
        int s = src[e], d = dst[e];
        int pos = atomicAdd(&cursor[d], 1);
        csr_src[pos] = s;
        csr_wt[pos]  = dinv[s] * dinv[d];
    }
}

// out[node,f] = dinv[node]^2 * feat[node,f] + sum_e csr_wt[e]*feat[csr_src[e],f]
__global__ __launch_bounds__(128) void agg_kernel(const float* __restrict__ feat,
                                                  const int* __restrict__ row_ptr,
                                                  const int* __restrict__ csr_src,
                                                  const float* __restrict__ csr_wt,
                                                  const float* __restrict__ dinv,
                                                  float* __restrict__ out, int n) {
    int node = blockIdx.x;
    int f = threadIdx.x;
    float di = dinv[node];
    float acc = feat[(size_t)node * 128 + f] * di * di;   // self-loop
    int e0 = row_ptr[node], e1 = row_ptr[node + 1];
    int e = e0;
    for (; e + 4 <= e1; e += 4) {
        int s0 = csr_src[e],   s1 = csr_src[e+1], s2 = csr_src[e+2], s3 = csr_src[e+3];
        float w0 = csr_wt[e],  w1 = csr_wt[e+1],  w2 = csr_wt[e+2],  w3 = csr_wt[e+3];
        float v0 = feat[(size_t)s0 * 128 + f];
        float v1 = feat[(size_t)s1 * 128 + f];
        float v2 = feat[(size_t)s2 * 128 + f];
        float v3 = feat[(size_t)s3 * 128 + f];
        acc += v0 * w0 + v1 * w1 + v2 * w2 + v3 * w3;
    }
    for (; e < e1; ++e)
        acc += feat[(size_t)csr_src[e] * 128 + f] * csr_wt[e];
    out[(size_t)node * 128 + f] = acc;
}

// ---------------------------------------------------------------------------
// C[N, 128-col chunk] = X[N,128] @ W[128, ldw] + bias, optional relu.
// Split-bf16 MFMA. LDS layout (per K-half of 64):
//   Xh/Xl: [row 0..127][k 0..63] bf16 (row stride 128B)
//   Wh/Wl: [col 0..127][k 0..63] bf16 (transposed during staging)
// byte-within-row = (2*k) ^ ((row&7)<<4)  -- T2 swizzle, both sides.
// Fragment maps (mfma_f32_16x16x32_bf16):
//   A: row = lane&15, k = (lane>>4)*8 + j   (8 contiguous k -> ds_read_b128)
//   B: col = lane&15, k = (lane>>4)*8 + j
//   C/D: col = lane&15, row = (lane>>4)*4 + reg   [guide m89-verified]
// ---------------------------------------------------------------------------
__global__ __launch_bounds__(256, 2) void gemm_mfma(const float* __restrict__ X,
                                                    const float* __restrict__ W,
                                                    const float* __restrict__ bias,
                                                    float* __restrict__ C,
                                                    int N, int ldw, int do_relu) {
    __shared__ ushort Xh[128 * 64];   // 16 KB each, 64 KB total -> 2 blocks/CU
    __shared__ ushort Xl[128 * 64];
    __shared__ ushort Wh[128 * 64];
    __shared__ ushort Wl[128 * 64];

    const int tid  = threadIdx.x;
    const int lane = tid & 63;
    const int wv   = tid >> 6;        // wave 0..3
    const int wr   = wv >> 1;         // wave row 0..1 (64 rows each)
    const int wc   = wv & 1;          // wave col 0..1 (64 cols each)
    const int lr   = lane & 15;
    const int lk   = lane >> 4;       // k-group 0..3
    const int row0   = blockIdx.y * 128;
    const int colOff = blockIdx.x * 128;

    f32x4 acc[4][4];
#pragma unroll
    for (int i = 0; i < 4; ++i)
#pragma unroll
        for (int j = 0; j < 4; ++j)
            acc[i][j] = (f32x4){0.f, 0.f, 0.f, 0.f};

    for (int ph = 0; ph < 2; ++ph) {
        if (ph) __syncthreads();      // prev compute done before overwrite

        // ---- stage X half-tile [128 rows][64 k], split hi/lo ----
        {
#pragma unroll
            for (int j = 0; j < 8; ++j) {
                int e   = tid + 256 * j;        // float4 index 0..2047
                int row = e >> 4;               // 0..127
                int k4  = e & 15;               // float4 within 64-k half
                int gr  = row0 + row; if (gr >= N) gr = N - 1;
                float4 v = *(const float4*)(X + (size_t)gr * 128 + ph * 64 + k4 * 4);
                ushort4 h, l;
                h.x = f2bf(v.x); h.y = f2bf(v.y); h.z = f2bf(v.z); h.w = f2bf(v.w);
                l.x = f2bf(v.x - bf2f(h.x));
                l.y = f2bf(v.y - bf2f(h.y));
                l.z = f2bf(v.z - bf2f(h.z));
                l.w = f2bf(v.w - bf2f(h.w));
                int byte = row * 128 + ((k4 * 8) ^ ((row & 7) << 4));
                *(ushort4*)((char*)Xh + byte) = h;
                *(ushort4*)((char*)Xl + byte) = l;
            }
        }
        // ---- stage W half-tile transposed -> [col][k], split hi/lo ----
        {
            const int c4 = tid & 31;            // 4-col group
            const int kg = tid >> 5;            // 0..7
#pragma unroll
            for (int q = 0; q < 2; ++q) {
                int kloc  = kg * 8 + q * 4;     // local k 0..60 (step 4)
                int kglob = ph * 64 + kloc;
                const float* wp = W + (size_t)kglob * ldw + colOff + c4 * 4;
                float4 v0 = *(const float4*)(wp);
                float4 v1 = *(const float4*)(wp + ldw);
                float4 v2 = *(const float4*)(wp + 2 * (size_t)ldw);
                float4 v3 = *(const float4*)(wp + 3 * (size_t)ldw);
#pragma unroll
                for (int j = 0; j < 4; ++j) {
                    float a0 = (&v0.x)[j], a1 = (&v1.x)[j], a2 = (&v2.x)[j], a3 = (&v3.x)[j];
                    ushort4 h, l;
                    h.x = f2bf(a0); h.y = f2bf(a1); h.z = f2bf(a2); h.w = f2bf(a3);
                    l.x = f2bf(a0 - bf2f(h.x));
                    l.y = f2bf(a1 - bf2f(h.y));
                    l.z = f2bf(a2 - bf2f(h.z));
                    l.w = f2bf(a3 - bf2f(h.w));
                    int col  = c4 * 4 + j;
                    int byte = col * 128 + ((kloc * 2) ^ ((col & 7) << 4));
                    *(ushort4*)((char*)Wh + byte) = h;
                    *(ushort4*)((char*)Wl + byte) = l;
                }
            }
        }
        __syncthreads();

        // ---- compute: 2 x K=32 chunks per phase ----
#pragma unroll
        for (int kk = 0; kk < 2; ++kk) {
            const int kb2 = (kk * 32 + lk * 8) * 2;   // byte offset pre-swizzle
            bf16x8 ah[4], al[4], bh[4], bl[4];
#pragma unroll
            for (int mi = 0; mi < 4; ++mi) {
                int row  = wr * 64 + mi * 16 + lr;
                int byte = row * 128 + (kb2 ^ ((row & 7) << 4));
                ah[mi] = *(const bf16x8*)((const char*)Xh + byte);
                al[mi] = *(const bf16x8*)((const char*)Xl + byte);
            }
#pragma unroll
            for (int ni = 0; ni < 4; ++ni) {
                int col  = wc * 64 + ni * 16 + lr;
                int byte = col * 128 + (kb2 ^ ((col & 7) << 4));
                bh[ni] = *(const bf16x8*)((const char*)Wh + byte);
                bl[ni] = *(const bf16x8*)((const char*)Wl + byte);
            }
#pragma unroll
            for (int mi = 0; mi < 4; ++mi)
#pragma unroll
                for (int ni = 0; ni < 4; ++ni) {
                    acc[mi][ni] = __builtin_amdgcn_mfma_f32_16x16x32_bf16(
                        ah[mi], bh[ni], acc[mi][ni], 0, 0, 0);
                    acc[mi][ni] = __builtin_amdgcn_mfma_f32_16x16x32_bf16(
                        ah[mi], bl[ni], acc[mi][ni], 0, 0, 0);
                    acc[mi][ni] = __builtin_amdgcn_mfma_f32_16x16x32_bf16(
                        al[mi], bh[ni], acc[mi][ni], 0, 0, 0);
                }
        }
    }

    // ---- epilogue: bias (+relu), scalar stores (64B/quarter-wave segments) ----
#pragma unroll
    for (int ni = 0; ni < 4; ++ni) {
        int col = colOff + wc * 64 + ni * 16 + lr;
        float bv = bias[col];
#pragma unroll
        for (int mi = 0; mi < 4; ++mi) {
            int rbase = row0 + wr * 64 + mi * 16 + (lane >> 4) * 4;
#pragma unroll
            for (int r = 0; r < 4; ++r) {
                int row = rbase + r;
                if (row < N) {
                    float v = acc[mi][ni][r] + bv;
                    if (do_relu) v = fmaxf(v, 0.f);
                    C[(size_t)row * ldw + col] = v;
                }
            }
        }
    }
}

// one 64-lane wave per query edge; load only the two selected heads (1 KB/edge)
__global__ __launch_bounds__(256) void query_kernel(const float* __restrict__ emb,
                                                    const int* __restrict__ qrow,
                                                    const int* __restrict__ qcol,
                                                    const int* __restrict__ y,
                                                    float* __restrict__ pred_i,
                                                    float* __restrict__ pred_j,
                                                    float* __restrict__ pred, int Q) {
    int wave = (int)((blockIdx.x * 256 + threadIdx.x) >> 6);
    int lane = threadIdx.x & 63;
    if (wave >= Q) return;
    int r = qrow[wave], c = qcol[wave];
    int yi = y[r], yj = y[c];   // same-address across wave -> broadcast
    const float* er = emb + (size_t)r * 512;
    const float* ec = emb + (size_t)c * 512;
    float pi = er[yi * 64 + lane] * ec[yi * 64 + lane];
    float pj = er[yj * 64 + lane] * ec[yj * 64 + lane];
#pragma unroll
    for (int off = 32; off >= 1; off >>= 1) {
        pi += __shfl_xor(pi, off, 64);
        pj += __shfl_xor(pj, off, 64);
    }
    if (lane == 0) {
        pred_i[wave] = pi;
        pred_j[wave] = pj;
        pred[wave]   = 0.5f * (pi + pj);
    }
}

extern "C" void kernel_launch(void* const* d_in, const int* in_sizes, int n_in,
                              void* d_out, int out_size, void* d_ws, size_t ws_size,
                              hipStream_t stream) {
    const float* x   = (const float*)d_in[0];
    const float* W1  = (const float*)d_in[1];
    const float* b1  = (const float*)d_in[2];
    const float* W2  = (const float*)d_in[3];
    const float* b2  = (const float*)d_in[4];
    const int* edge  = (const int*)d_in[5];
    const int* qedge = (const int*)d_in[6];
    const int* y     = (const int*)d_in[7];

    const int N = in_sizes[0] / 128;   // 100000
    const int E = in_sizes[5] / 2;     // 1600000
    const int Q = in_sizes[6] / 2;     // 400000

    float* out     = (float*)d_out;
    float* hiddens = out;                         // [N,128]
    float* emb     = out + (size_t)N * 128;       // [N,512]
    float* pred_i  = emb + (size_t)N * 512;       // [Q]
    float* pred_j  = pred_i + Q;                  // [Q]
    float* pred    = pred_j + Q;                  // [Q]

    // workspace carve (256B aligned)
    char* w = (char*)d_ws;
    auto alloc = [&](size_t bytes) { char* p = w; w += (bytes + 255) & ~(size_t)255; return p; };
    int*   cnt      = (int*)alloc((size_t)N * 4);
    int*   row_ptr  = (int*)alloc((size_t)(N + 1) * 4);
    int*   cursor   = (int*)alloc((size_t)N * 4);
    float* dinv     = (float*)alloc((size_t)N * 4);
    int*   csr_src  = (int*)alloc((size_t)E * 4);
    float* csr_wt   = (float*)alloc((size_t)E * 4);
    int*   blocksum = (int*)alloc(256 * 4);
    int*   blockoff = (int*)alloc(256 * 4);
    float* aggbuf   = (float*)alloc((size_t)N * 128 * 4);  // 51.2 MB, reused

    const int* esrc = edge;         const int* edst = edge + E;
    const int* qrow = qedge;        const int* qcol = qedge + Q;

    const int nb = (N + SCAN_SEG - 1) / SCAN_SEG;   // 196 <= 256

    hipMemsetAsync(cnt, 0, (size_t)N * 4, stream);
    count_kernel<<<dim3((E + 255) / 256), dim3(256), 0, stream>>>(edst, cnt, E);
    blocksum_kernel<<<dim3(nb), dim3(256), 0, stream>>>(cnt, blocksum, N);
    blockscan_kernel<<<dim3(1), dim3(256), 0, stream>>>(blocksum, blockoff, nb, row_ptr, N, E);
    csr_ptr_kernel<<<dim3(nb), dim3(256), 0, stream>>>(cnt, blockoff, row_ptr, cursor, dinv, N);
    fill_kernel<<<dim3((E + 255) / 256), dim3(256), 0, stream>>>(esrc, edst, cursor, dinv, csr_src, csr_wt, E);

    const int mblocks = (N + 127) / 128;   // 782

    // layer 1: aggregate x, then split-bf16 MFMA GEMM with fused bias+relu
    agg_kernel<<<dim3(N), dim3(128), 0, stream>>>(x, row_ptr, csr_src, csr_wt, dinv, aggbuf, N);
    gemm_mfma<<<dim3(1, mblocks), dim3(256), 0, stream>>>(aggbuf, W1, b1, hiddens, N, 128, 1);

    // layer 2: aggregate hiddens, then split-bf16 MFMA GEMM with fused bias
    agg_kernel<<<dim3(N), dim3(128), 0, stream>>>(hiddens, row_ptr, csr_src, csr_wt, dinv, aggbuf, N);
    gemm_mfma<<<dim3(4, mblocks), dim3(256), 0, stream>>>(aggbuf, W2, b2, emb, N, 512, 0);

    query_kernel<<<dim3((Q + 3) / 4), dim3(256), 0, stream>>>(emb, qrow, qcol, y, pred_i, pred_j, pred, Q);
}

// Round 3
// 945.801 us; speedup vs baseline: 1.1850x; 1.0176x over previous
//
#include <hip/hip_runtime.h>
#include <hip/hip_bf16.h>

// ---------------------------------------------------------------------------
// GNN: hiddens = relu(gcn(x,W1,b1)); emb = gcn(hiddens,W2,b2);
// pred_i/j = <emb[r,y,:],emb[c,y,:]> at head y[r]/y[c].
//
// aggregate-then-transform: A_norm @ (H @ W) = (A_norm @ H) @ W.
// CSR build: count -> 3-phase parallel scan -> atomic fill with per-edge norm.
// agg: wave/node, 2x32-lane edge groups, float4 gathers, writes bf16 hi/lo
//      (split hoisted out of GEMM; identical rounding to fp32 path).
// GEMM: split-bf16 MFMA (C = Ah*Bh + Ah*Bl + Al*Bh, fp32 accumulate).
//   128x128 tile, 4 waves (2x2), wave tile 64x64 = 4x4 frags of 16x16x32.
//   BK=64 two-phase staging, 64KB LDS -> 2 blocks/CU. Staging is a pure
//   swizzled 16B copy (W pre-transposed/split by prep kernel).
// ---------------------------------------------------------------------------

#define SCAN_SEG 512   // elements per scan block (256 threads x 2)

typedef short bf16x8 __attribute__((ext_vector_type(8)));   // 8 bf16 in 4 VGPRs
typedef float f32x4  __attribute__((ext_vector_type(4)));

__device__ __forceinline__ ushort f2bf(float x) {           // truncate: lo term catches residual
    return (ushort)(__float_as_uint(x) >> 16);
}
__device__ __forceinline__ float bf2f(ushort h) {
    return __uint_as_float(((unsigned)h) << 16);
}

__global__ void count_kernel(const int* __restrict__ dst, int* __restrict__ cnt, int E) {
    int e = blockIdx.x * blockDim.x + threadIdx.x;
    if (e < E) atomicAdd(&cnt[dst[e]], 1);
}

// phase 1: per-block segment sums (coalesced)
__global__ __launch_bounds__(256) void blocksum_kernel(const int* __restrict__ cnt,
                                                       int* __restrict__ blocksum, int n) {
    __shared__ int red[4];
    int b = blockIdx.x, t = threadIdx.x;
    int i0 = b * SCAN_SEG + t;
    int s = 0;
    if (i0 < n) s += cnt[i0];
    if (i0 + 256 < n) s += cnt[i0 + 256];
#pragma unroll
    for (int off = 32; off >= 1; off >>= 1) s += __shfl_xor(s, off, 64);
    if ((t & 63) == 0) red[t >> 6] = s;
    __syncthreads();
    if (t == 0) blocksum[b] = red[0] + red[1] + red[2] + red[3];
}

// phase 2: exclusive scan of <=256 block sums in one small block
__global__ __launch_bounds__(256) void blockscan_kernel(const int* __restrict__ blocksum,
                                                        int* __restrict__ blockoff, int nb,
                                                        int* __restrict__ row_ptr, int n, int E) {
    __shared__ int s[256];
    int t = threadIdx.x;
    int v = (t < nb) ? blocksum[t] : 0;
    s[t] = v;
    __syncthreads();
    for (int off = 1; off < 256; off <<= 1) {
        int u = (t >= off) ? s[t - off] : 0;
        __syncthreads();
        s[t] += u;
        __syncthreads();
    }
    if (t < nb) blockoff[t] = s[t] - v;   // exclusive
    if (t == 0) row_ptr[n] = E;
}

// phase 3: per-block exclusive scan over its 512-elem segment -> row_ptr/cursor/dinv
__global__ __launch_bounds__(256) void csr_ptr_kernel(const int* __restrict__ cnt,
                                                      const int* __restrict__ blockoff,
                                                      int* __restrict__ row_ptr,
                                                      int* __restrict__ cursor,
                                                      float* __restrict__ dinv, int n) {
    __shared__ int s[256];
    int b = blockIdx.x, t = threadIdx.x;
    int i0 = b * SCAN_SEG + 2 * t;       // thread handles i0, i0+1
    int c0 = (i0     < n) ? cnt[i0]     : 0;
    int c1 = (i0 + 1 < n) ? cnt[i0 + 1] : 0;
    int pair = c0 + c1;
    s[t] = pair;
    __syncthreads();
    for (int off = 1; off < 256; off <<= 1) {
        int u = (t >= off) ? s[t - off] : 0;
        __syncthreads();
        s[t] += u;
        __syncthreads();
    }
    int excl = s[t] - pair + blockoff[b];
    if (i0 < n) {
        row_ptr[i0] = excl;
        cursor[i0]  = excl;
        dinv[i0]    = rsqrtf((float)(c0 + 1));
    }
    if (i0 + 1 < n) {
        row_ptr[i0 + 1] = excl + c0;
        cursor[i0 + 1]  = excl + c0;
        dinv[i0 + 1]    = rsqrtf((float)(c1 + 1));
    }
}

__global__ void fill_kernel(const int* __restrict__ src, const int* __restrict__ dst,
                            int* __restrict__ cursor, const float* __restrict__ dinv,
                            int* __restrict__ csr_src, float* __restrict__ csr_wt, int E) {
    int e = blockIdx.x * blockDim.x + threadIdx.x;
    if (e < E) {
        int s = src[e], d = dst[e];
        int pos = atomicAdd(&cursor[d], 1);
        csr_src[pos] = s;
        csr_wt[pos]  = dinv[s] * dinv[d];
    }
}

// W[k][ncols] fp32 -> Wt_h/Wt_l[col][k] bf16 hi/lo (transposed, split). Tiny, once.
__global__ __launch_bounds__(256) void wsplit_kernel(const float* __restrict__ W,
                                                     ushort* __restrict__ th,
                                                     ushort* __restrict__ tl, int ncols) {
    int idx = blockIdx.x * 256 + threadIdx.x;   // over 128*ncols
    if (idx >= 128 * ncols) return;
    int col = idx >> 7;
    int k   = idx & 127;
    float v = W[(size_t)k * ncols + col];
    ushort h = f2bf(v);
    th[idx] = h;
    tl[idx] = f2bf(v - bf2f(h));
}

// agg: out_{h,l}[node,f] = split( dinv^2*feat[node,f] + sum_e wt[e]*feat[src[e],f] )
// one wave per node; two 32-lane groups each own alternate edges; float4 gathers.
__global__ __launch_bounds__(256) void agg_kernel(const float* __restrict__ feat,
                                                  const int* __restrict__ row_ptr,
                                                  const int* __restrict__ csr_src,
                                                  const float* __restrict__ csr_wt,
                                                  const float* __restrict__ dinv,
                                                  ushort* __restrict__ outh,
                                                  ushort* __restrict__ outl, int n) {
    const int w    = threadIdx.x >> 6;         // wave 0..3
    const int lane = threadIdx.x & 63;
    const int node = blockIdx.x * 4 + w;
    if (node >= n) return;
    const int g = lane >> 5;                   // edge-parity group 0/1
    const int c = lane & 31;                   // float4 column index (covers 128 feats)

    float di = dinv[node];
    float4 acc = make_float4(0.f, 0.f, 0.f, 0.f);
    if (g == 0) {                              // self-loop message
        float4 v = ((const float4*)(feat + (size_t)node * 128))[c];
        float s2 = di * di;
        acc.x = v.x * s2; acc.y = v.y * s2; acc.z = v.z * s2; acc.w = v.w * s2;
    }

    int e0 = row_ptr[node], e1 = row_ptr[node + 1];
    int e = e0 + g;
    for (; e + 2 < e1; e += 4) {               // 2 edges per group in flight
        int   s0 = csr_src[e],  s1 = csr_src[e + 2];
        float w0 = csr_wt[e],   w1 = csr_wt[e + 2];
        float4 v0 = ((const float4*)(feat + (size_t)s0 * 128))[c];
        float4 v1 = ((const float4*)(feat + (size_t)s1 * 128))[c];
        acc.x += v0.x * w0 + v1.x * w1;
        acc.y += v0.y * w0 + v1.y * w1;
        acc.z += v0.z * w0 + v1.z * w1;
        acc.w += v0.w * w0 + v1.w * w1;
    }
    for (; e < e1; e += 2) {
        int   s0 = csr_src[e];
        float w0 = csr_wt[e];
        float4 v0 = ((const float4*)(feat + (size_t)s0 * 128))[c];
        acc.x += v0.x * w0; acc.y += v0.y * w0; acc.z += v0.z * w0; acc.w += v0.w * w0;
    }

    // combine the two edge groups
    acc.x += __shfl_xor(acc.x, 32, 64);
    acc.y += __shfl_xor(acc.y, 32, 64);
    acc.z += __shfl_xor(acc.z, 32, 64);
    acc.w += __shfl_xor(acc.w, 32, 64);

    if (g == 0) {
        ushort4 h, l;
        h.x = f2bf(acc.x); l.x = f2bf(acc.x - bf2f(h.x));
        h.y = f2bf(acc.y); l.y = f2bf(acc.y - bf2f(h.y));
        h.z = f2bf(acc.z); l.z = f2bf(acc.z - bf2f(h.z));
        h.w = f2bf(acc.w); l.w = f2bf(acc.w - bf2f(h.w));
        *(ushort4*)(outh + (size_t)node * 128 + c * 4) = h;
        *(ushort4*)(outl + (size_t)node * 128 + c * 4) = l;
    }
}

// ---------------------------------------------------------------------------
// C[N, 128-col chunk] = X @ W + bias (split-bf16 MFMA), inputs pre-split:
//   Xh/Xl: [N][128] bf16 row-major; Wth/Wtl: [colG][128] bf16 (pre-transposed).
// LDS per half-K: [row|col 0..127][k 0..63] bf16, 16B-chunk XOR swizzle
//   chunkidx ^= (row&7)  (byte ^ ((row&7)<<4)), both write and read sides.
// Fragment maps (mfma_f32_16x16x32_bf16):
//   A: row=lane&15, k=(lane>>4)*8+j ; B: col=lane&15, same k
//   C/D: col=lane&15, row=(lane>>4)*4+reg   [guide m89-verified]
// ---------------------------------------------------------------------------
__global__ __launch_bounds__(256, 2) void gemm_mfma(const ushort* __restrict__ Xh_g,
                                                    const ushort* __restrict__ Xl_g,
                                                    const ushort* __restrict__ Wth_g,
                                                    const ushort* __restrict__ Wtl_g,
                                                    const float* __restrict__ bias,
                                                    float* __restrict__ C,
                                                    int N, int ldw, int do_relu) {
    __shared__ ushort Xh[128 * 64];   // 16 KB each, 64 KB total -> 2 blocks/CU
    __shared__ ushort Xl[128 * 64];
    __shared__ ushort Wh[128 * 64];
    __shared__ ushort Wl[128 * 64];

    const int tid  = threadIdx.x;
    const int lane = tid & 63;
    const int wv   = tid >> 6;        // wave 0..3
    const int wr   = wv >> 1;         // wave row 0..1 (64 rows each)
    const int wc   = wv & 1;          // wave col 0..1 (64 cols each)
    const int lr   = lane & 15;
    const int lk   = lane >> 4;       // k-group 0..3
    const int row0   = blockIdx.y * 128;
    const int colOff = blockIdx.x * 128;

    f32x4 acc[4][4];
#pragma unroll
    for (int i = 0; i < 4; ++i)
#pragma unroll
        for (int j = 0; j < 4; ++j)
            acc[i][j] = (f32x4){0.f, 0.f, 0.f, 0.f};

    for (int ph = 0; ph < 2; ++ph) {
        if (ph) __syncthreads();      // prev compute done before overwrite

        // ---- stage X half-tile: pure swizzled 16B copies ----
#pragma unroll
        for (int q = 0; q < 4; ++q) {
            int cidx = tid + 256 * q;            // 16B-chunk id 0..1023
            int row  = cidx >> 3;                // 0..127
            int kch  = cidx & 7;                 // 16B chunk within 64-k half
            int gr   = row0 + row; if (gr >= N) gr = N - 1;
            size_t ge = (size_t)gr * 128 + ph * 64 + kch * 8;
            int lb = row * 128 + ((kch * 16) ^ ((row & 7) << 4));
            *(int4*)((char*)Xh + lb) = *(const int4*)(Xh_g + ge);
            *(int4*)((char*)Xl + lb) = *(const int4*)(Xl_g + ge);
        }
        // ---- stage W half-tile (already transposed/split in global) ----
#pragma unroll
        for (int q = 0; q < 4; ++q) {
            int cidx = tid + 256 * q;
            int col  = cidx >> 3;
            int kch  = cidx & 7;
            size_t ge = (size_t)(colOff + col) * 128 + ph * 64 + kch * 8;
            int lb = col * 128 + ((kch * 16) ^ ((col & 7) << 4));
            *(int4*)((char*)Wh + lb) = *(const int4*)(Wth_g + ge);
            *(int4*)((char*)Wl + lb) = *(const int4*)(Wtl_g + ge);
        }
        __syncthreads();

        // ---- compute: 2 x K=32 chunks per phase ----
#pragma unroll
        for (int kk = 0; kk < 2; ++kk) {
            const int kb2 = (kk * 32 + lk * 8) * 2;   // byte offset pre-swizzle
            bf16x8 ah[4], al[4], bh[4], bl[4];
#pragma unroll
            for (int mi = 0; mi < 4; ++mi) {
                int row  = wr * 64 + mi * 16 + lr;
                int byte = row * 128 + (kb2 ^ ((row & 7) << 4));
                ah[mi] = *(const bf16x8*)((const char*)Xh + byte);
                al[mi] = *(const bf16x8*)((const char*)Xl + byte);
            }
#pragma unroll
            for (int ni = 0; ni < 4; ++ni) {
                int col  = wc * 64 + ni * 16 + lr;
                int byte = col * 128 + (kb2 ^ ((col & 7) << 4));
                bh[ni] = *(const bf16x8*)((const char*)Wh + byte);
                bl[ni] = *(const bf16x8*)((const char*)Wl + byte);
            }
#pragma unroll
            for (int mi = 0; mi < 4; ++mi)
#pragma unroll
                for (int ni = 0; ni < 4; ++ni) {
                    acc[mi][ni] = __builtin_amdgcn_mfma_f32_16x16x32_bf16(
                        ah[mi], bh[ni], acc[mi][ni], 0, 0, 0);
                    acc[mi][ni] = __builtin_amdgcn_mfma_f32_16x16x32_bf16(
                        ah[mi], bl[ni], acc[mi][ni], 0, 0, 0);
                    acc[mi][ni] = __builtin_amdgcn_mfma_f32_16x16x32_bf16(
                        al[mi], bh[ni], acc[mi][ni], 0, 0, 0);
                }
        }
    }

    // ---- epilogue: bias (+relu), scalar stores (64B/quarter-wave segments) ----
#pragma unroll
    for (int ni = 0; ni < 4; ++ni) {
        int col = colOff + wc * 64 + ni * 16 + lr;
        float bv = bias[col];
#pragma unroll
        for (int mi = 0; mi < 4; ++mi) {
            int rbase = row0 + wr * 64 + mi * 16 + (lane >> 4) * 4;
#pragma unroll
            for (int r = 0; r < 4; ++r) {
                int row = rbase + r;
                if (row < N) {
                    float v = acc[mi][ni][r] + bv;
                    if (do_relu) v = fmaxf(v, 0.f);
                    C[(size_t)row * ldw + col] = v;
                }
            }
        }
    }
}

// one wave per query edge; 4 lane-groups of 16 gather the 4 head-vectors in
// ONE float4 issue; shfl_xor(16) pairs er*ec; 16-lane reduce; shfl_xor(32)
// marries pi (lanes 0..31) with pj (lanes 32..63).
__global__ __launch_bounds__(256) void query_kernel(const float* __restrict__ emb,
                                                    const int* __restrict__ qrow,
                                                    const int* __restrict__ qcol,
                                                    const int* __restrict__ y,
                                                    float* __restrict__ pred_i,
                                                    float* __restrict__ pred_j,
                                                    float* __restrict__ pred, int Q) {
    int wave = (int)((blockIdx.x * 256 + threadIdx.x) >> 6);
    int lane = threadIdx.x & 63;
    if (wave >= Q) return;
    int r = qrow[wave], c = qcol[wave];
    int yr = y[r], yc = y[c];                  // uniform -> broadcast loads
    int g = lane >> 4;                         // 0: emb[r,yr] 1: emb[c,yr] 2: emb[r,yc] 3: emb[c,yc]
    int t = lane & 15;
    int node = (g & 1) ? c : r;
    int head = (g >> 1) ? yc : yr;
    const float4* p = (const float4*)(emb + (size_t)node * 512 + head * 64);
    float4 v = p[t];
    float4 o;
    o.x = __shfl_xor(v.x, 16, 64);
    o.y = __shfl_xor(v.y, 16, 64);
    o.z = __shfl_xor(v.z, 16, 64);
    o.w = __shfl_xor(v.w, 16, 64);
    float s = v.x * o.x + v.y * o.y + v.z * o.z + v.w * o.w;
#pragma unroll
    for (int off = 8; off >= 1; off >>= 1) s += __shfl_xor(s, off, 64);
    float other = __shfl_xor(s, 32, 64);       // lane0: pj
    if (lane == 0) {
        pred_i[wave] = s;
        pred_j[wave] = other;
        pred[wave]   = 0.5f * (s + other);
    }
}

extern "C" void kernel_launch(void* const* d_in, const int* in_sizes, int n_in,
                              void* d_out, int out_size, void* d_ws, size_t ws_size,
                              hipStream_t stream) {
    const float* x   = (const float*)d_in[0];
    const float* W1  = (const float*)d_in[1];
    const float* b1  = (const float*)d_in[2];
    const float* W2  = (const float*)d_in[3];
    const float* b2  = (const float*)d_in[4];
    const int* edge  = (const int*)d_in[5];
    const int* qedge = (const int*)d_in[6];
    const int* y     = (const int*)d_in[7];

    const int N = in_sizes[0] / 128;   // 100000
    const int E = in_sizes[5] / 2;     // 1600000
    const int Q = in_sizes[6] / 2;     // 400000

    float* out     = (float*)d_out;
    float* hiddens = out;                         // [N,128]
    float* emb     = out + (size_t)N * 128;       // [N,512]
    float* pred_i  = emb + (size_t)N * 512;       // [Q]
    float* pred_j  = pred_i + Q;                  // [Q]
    float* pred    = pred_j + Q;                  // [Q]

    // workspace carve (256B aligned)
    char* w = (char*)d_ws;
    auto alloc = [&](size_t bytes) { char* p = w; w += (bytes + 255) & ~(size_t)255; return p; };
    int*    cnt      = (int*)alloc((size_t)N * 4);
    int*    row_ptr  = (int*)alloc((size_t)(N + 1) * 4);
    int*    cursor   = (int*)alloc((size_t)N * 4);
    float*  dinv     = (float*)alloc((size_t)N * 4);
    int*    csr_src  = (int*)alloc((size_t)E * 4);
    float*  csr_wt   = (float*)alloc((size_t)E * 4);
    int*    blocksum = (int*)alloc(256 * 4);
    int*    blockoff = (int*)alloc(256 * 4);
    ushort* aggh     = (ushort*)alloc((size_t)N * 128 * 2);   // 25.6 MB
    ushort* aggl     = (ushort*)alloc((size_t)N * 128 * 2);   // 25.6 MB
    ushort* w1h      = (ushort*)alloc(128 * 128 * 2);
    ushort* w1l      = (ushort*)alloc(128 * 128 * 2);
    ushort* w2h      = (ushort*)alloc(128 * 512 * 2);
    ushort* w2l      = (ushort*)alloc(128 * 512 * 2);

    const int* esrc = edge;         const int* edst = edge + E;
    const int* qrow = qedge;        const int* qcol = qedge + Q;

    const int nb = (N + SCAN_SEG - 1) / SCAN_SEG;   // 196 <= 256

    hipMemsetAsync(cnt, 0, (size_t)N * 4, stream);
    count_kernel<<<dim3((E + 255) / 256), dim3(256), 0, stream>>>(edst, cnt, E);
    blocksum_kernel<<<dim3(nb), dim3(256), 0, stream>>>(cnt, blocksum, N);
    blockscan_kernel<<<dim3(1), dim3(256), 0, stream>>>(blocksum, blockoff, nb, row_ptr, N, E);
    csr_ptr_kernel<<<dim3(nb), dim3(256), 0, stream>>>(cnt, blockoff, row_ptr, cursor, dinv, N);
    fill_kernel<<<dim3((E + 255) / 256), dim3(256), 0, stream>>>(esrc, edst, cursor, dinv, csr_src, csr_wt, E);

    // one-time weight transpose+split (tiny)
    wsplit_kernel<<<dim3((128 * 128 + 255) / 256), dim3(256), 0, stream>>>(W1, w1h, w1l, 128);
    wsplit_kernel<<<dim3((128 * 512 + 255) / 256), dim3(256), 0, stream>>>(W2, w2h, w2l, 512);

    const int mblocks = (N + 127) / 128;   // 782
    const int ablocks = (N + 3) / 4;       // 25000

    // layer 1: aggregate x (split output), then MFMA GEMM with fused bias+relu
    agg_kernel<<<dim3(ablocks), dim3(256), 0, stream>>>(x, row_ptr, csr_src, csr_wt, dinv, aggh, aggl, N);
    gemm_mfma<<<dim3(1, mblocks), dim3(256), 0, stream>>>(aggh, aggl, w1h, w1l, b1, hiddens, N, 128, 1);

    // layer 2: aggregate hiddens, then MFMA GEMM with fused bias
    agg_kernel<<<dim3(ablocks), dim3(256), 0, stream>>>(hiddens, row_ptr, csr_src, csr_wt, dinv, aggh, aggl, N);
    gemm_mfma<<<dim3(4, mblocks), dim3(256), 0, stream>>>(aggh, aggl, w2h, w2l, b2, emb, N, 512, 0);

    query_kernel<<<dim3((Q + 3) / 4), dim3(256), 0, stream>>>(emb, qrow, qcol, y, pred_i, pred_j, pred, Q);
}